// Round 2
// baseline (150.652 us; speedup 1.0000x reference)
//
#include <hip/hip_runtime.h>
#include <hip/hip_cooperative_groups.h>

namespace cg = cooperative_groups;

// Problem constants
#define D_B 8
#define N_T 2048
#define NN  64
#define N_H 8
#define N_C 32   // u-chunks of 64

typedef __bf16 bf16;
typedef bf16 bf16x8 __attribute__((ext_vector_type(8)));
typedef bf16 bf16x4 __attribute__((ext_vector_type(4)));
typedef float f32x4 __attribute__((ext_vector_type(4)));

// Dynamic LDS layout (bytes):
//   [0,      9216)   Rl   : r' chunk bf16 [u][j], stride 72   (phase 1)
//                    Gb   : Gcum bf16 [i][i'], stride 72      (phase 2/3)
//   [9216,  82944)   Qrl  : 8 heads x (64x72) bf16 [u][i]     (phase 1 -> 3)
//   [82944, 101376)  QT   : 64x72 bf16 [i'][u]  (phase 1, per-head scratch)
//         +ET at 92160: 64x72 bf16 [i][u]
//                    Sl   : 8 waves x 16x72 bf16 S-slabs      (phase 3)
//                    Ob   : 64x65 f32 reduction tile          (phase 3 tail)
#define SMEM_BYTES 101376

static __device__ __forceinline__ f32x4 mfma16(bf16x8 a, bf16x8 b, f32x4 c) {
    // a_frag[j] = A[lane&15][(lane>>4)*8+j]; b_frag[j] = B[(lane>>4)*8+j][lane&15]
    // d[r] = D[(lane>>4)*4+r][lane&15]
    return __builtin_amdgcn_mfma_f32_16x16x32_bf16(a, b, c, 0, 0, 0);
}

static __device__ __forceinline__ bf16x8 ldcvt8(const float* p) {
    const f32x4 v0 = *(const f32x4*)p;
    const f32x4 v1 = *(const f32x4*)(p + 4);
    bf16x8 r;
#pragma unroll
    for (int k = 0; k < 4; k++) { r[k] = (bf16)v0[k]; r[4 + k] = (bf16)v1[k]; }
    return r;
}

__global__ __launch_bounds__(512, 2) void k_fused(
    const float* __restrict__ rp, const float* __restrict__ Qm,
    const float* __restrict__ Em,
    bf16* __restrict__ ErT, bf16* __restrict__ dGb, float* __restrict__ out)
{
    extern __shared__ char smem[];
    bf16* Rl  = (bf16*)smem;
    bf16* Qrl = (bf16*)(smem + 9216);
    bf16* QT  = (bf16*)(smem + 82944);
    bf16* ET  = (bf16*)(smem + 92160);
    bf16* Sl  = (bf16*)(smem + 82944);
    float* Ob = (float*)(smem + 82944);
    bf16* Gb  = (bf16*)smem;

    const int c = blockIdx.x, b = blockIdx.y;
    const int tid = threadIdx.x;
    const int w = tid >> 6, l = tid & 63, q = l >> 4, l16 = l & 15;
    const int g = w >> 2, w2 = w & 3;

    // ---------------- Phase 1: stage R; compute Qr (LDS), Er (->global ErT), dG
    {
        const int row = tid >> 3, col = (tid & 7) * 8;
        const float* src = rp + ((size_t)(b * N_T) + c * 64 + row) * NN + col;
        *(bf16x8*)&Rl[row * 72 + col] = ldcvt8(src);
    }
    __syncthreads();
    // A-frags: R rows w2*16+l16 (identical role in phase 1 and phase 3)
    const bf16x8 a0 = *(const bf16x8*)&Rl[(w2 * 16 + l16) * 72 + q * 8];
    const bf16x8 a1 = *(const bf16x8*)&Rl[(w2 * 16 + l16) * 72 + 32 + q * 8];

    f32x4 dg0 = {0.f, 0.f, 0.f, 0.f};
    f32x4 dg1 = {0.f, 0.f, 0.f, 0.f};

    for (int h = 0; h < N_H; h++) {
        // B-frags straight from global fp32 (L2-resident; Q/E = 128 KB each)
        const float* Bsrc = (g == 0) ? (Qm + (size_t)h * 4096) : (Em + (size_t)h * 4096);
#pragma unroll
        for (int ns = 0; ns < 4; ns++) {
            const bf16x8 b0 = ldcvt8(Bsrc + (ns * 16 + l16) * 64 + q * 8);
            const bf16x8 b1 = ldcvt8(Bsrc + (ns * 16 + l16) * 64 + 32 + q * 8);
            f32x4 z = {0.f, 0.f, 0.f, 0.f};
            f32x4 s = mfma16(a0, b0, z);
            s = mfma16(a1, b1, s);
            // C/D: row u_loc = w2*16+q*4+r, col i = ns*16+l16
            bf16x4 p;
#pragma unroll
            for (int r = 0; r < 4; r++) p[r] = (bf16)s[r];
            if (g == 0) {
#pragma unroll
                for (int r = 0; r < 4; r++)
                    Qrl[h * 4608 + (w2 * 16 + q * 4 + r) * 72 + ns * 16 + l16] = p[r];
                *(bf16x4*)&QT[(ns * 16 + l16) * 72 + w2 * 16 + q * 4] = p;
            } else {
                *(bf16x4*)&ET[(ns * 16 + l16) * 72 + w2 * 16 + q * 4] = p;
            }
        }
        __syncthreads();   // QT/ET complete
        // dG accumulate: wave (w2,g): rows i' = w2-slab, cols g*32 + {0,16}
        {
            const bf16x8 qa0 = *(const bf16x8*)&QT[(w2 * 16 + l16) * 72 + q * 8];
            const bf16x8 qa1 = *(const bf16x8*)&QT[(w2 * 16 + l16) * 72 + 32 + q * 8];
            {
                const int col = g * 32;
                const bf16x8 e0 = *(const bf16x8*)&ET[(col + l16) * 72 + q * 8];
                const bf16x8 e1 = *(const bf16x8*)&ET[(col + l16) * 72 + 32 + q * 8];
                dg0 = mfma16(qa0, e0, dg0);
                dg0 = mfma16(qa1, e1, dg0);
            }
            {
                const int col = g * 32 + 16;
                const bf16x8 e0 = *(const bf16x8*)&ET[(col + l16) * 72 + q * 8];
                const bf16x8 e1 = *(const bf16x8*)&ET[(col + l16) * 72 + 32 + q * 8];
                dg1 = mfma16(qa0, e0, dg1);
                dg1 = mfma16(qa1, e1, dg1);
            }
        }
        // flush ET tile to global ErT (coalesced); read by THIS block in phase 3
        {
            const int row = tid >> 3, col = (tid & 7) * 8;  // row=i, col=u_loc
            const bf16x8 v = *(const bf16x8*)&ET[row * 72 + col];
            *(bf16x8*)&ErT[((size_t)(b * N_H + h) * NN + row) * N_T + c * 64 + col] = v;
        }
        __syncthreads();   // before next head overwrites QT/ET
    }
    // write dG (bf16, [b,c,i',i])
    {
        bf16* dst = dGb + (size_t)(b * N_C + c) * 4096;
#pragma unroll
        for (int r = 0; r < 4; r++) {
            dst[(w2 * 16 + q * 4 + r) * 64 + g * 32 + l16] = (bf16)dg0[r];
            dst[(w2 * 16 + q * 4 + r) * 64 + g * 32 + 16 + l16] = (bf16)dg1[r];
        }
    }

    cg::this_grid().sync();

    // ---------------- Phase 2: Gcum[b,c] = sum_{c'<c} dG[b,c'] -> Gb LDS [i][i']
    {
        float run[8];
#pragma unroll
        for (int k = 0; k < 8; k++) run[k] = 0.f;
        const bf16* dgbase = dGb + (size_t)b * N_C * 4096 + tid * 8;
        for (int cp = 0; cp < c; cp++) {
            const bf16x8 v = *(const bf16x8*)(dgbase + (size_t)cp * 4096);
#pragma unroll
            for (int k = 0; k < 8; k++) run[k] += (float)v[k];
        }
        const int ip = tid >> 3, ii0 = (tid & 7) * 8;  // element = ip*64 + ii0+k
#pragma unroll
        for (int k = 0; k < 8; k++) Gb[(ii0 + k) * 72 + ip] = (bf16)run[k];
    }
    __syncthreads();

    // ---------------- Phase 3: O = R*Gcum (g==1) + sum_h tril(R Qr_h^T) Er_h
    bf16* Sw = Sl + w * 1152;   // per-wave 16x72 S slab
    f32x4 acc[4];
#pragma unroll
    for (int ns = 0; ns < 4; ns++) { f32x4 z = {0.f, 0.f, 0.f, 0.f}; acc[ns] = z; }

    for (int hh = 0; hh < 4; hh++) {
        const int h = g * 4 + hh;
        const bf16* Qh = Qrl + h * 4608;
        const bf16* Ert = ErT + (size_t)(b * N_H + h) * NN * N_T + c * 64;
        // S[t_loc][u_loc] = sum_i' R[t,i'] Qr[u,i'] (B-frags from LDS Qrl)
#pragma unroll
        for (int ns = 0; ns < 4; ns++) {
            const bf16x8 b0 = *(const bf16x8*)&Qh[(ns * 16 + l16) * 72 + q * 8];
            const bf16x8 b1 = *(const bf16x8*)&Qh[(ns * 16 + l16) * 72 + 32 + q * 8];
            f32x4 z = {0.f, 0.f, 0.f, 0.f};
            f32x4 sv = mfma16(a0, b0, z);
            sv = mfma16(a1, b1, sv);
            const int u_loc = ns * 16 + l16;
#pragma unroll
            for (int r = 0; r < 4; r++) {
                const int t_loc = w2 * 16 + q * 4 + r;
                const float vv = (u_loc <= t_loc) ? sv[r] : 0.f;
                Sw[(q * 4 + r) * 72 + u_loc] = (bf16)vv;
            }
        }
        // same-wave LDS RAW (in-order DS per wave); S back as A-operand
        const bf16x8 sa0 = *(const bf16x8*)&Sw[l16 * 72 + q * 8];
        const bf16x8 sa1 = *(const bf16x8*)&Sw[l16 * 72 + 32 + q * 8];
        // O += S * Er  (B-frags from global ErT, same-XCD L2 hot)
#pragma unroll
        for (int ns = 0; ns < 4; ns++) {
            const bf16x8 e0 = *(const bf16x8*)&Ert[(size_t)(ns * 16 + l16) * N_T + q * 8];
            const bf16x8 e1 = *(const bf16x8*)&Ert[(size_t)(ns * 16 + l16) * N_T + 32 + q * 8];
            acc[ns] = mfma16(sa0, e0, acc[ns]);
            acc[ns] = mfma16(sa1, e1, acc[ns]);
        }
    }
    // prefix contribution (g==1): O += R * Gcum (B-frags from Gb [i][i'])
    if (g == 1) {
#pragma unroll
        for (int ns = 0; ns < 4; ns++) {
            const bf16x8 g0 = *(const bf16x8*)&Gb[(ns * 16 + l16) * 72 + q * 8];
            const bf16x8 g1 = *(const bf16x8*)&Gb[(ns * 16 + l16) * 72 + 32 + q * 8];
            acc[ns] = mfma16(a0, g0, acc[ns]);
            acc[ns] = mfma16(a1, g1, acc[ns]);
        }
    }
    __syncthreads();   // all S reads done before Ob overwrites the S region
    if (g == 0) {
#pragma unroll
        for (int ns = 0; ns < 4; ns++)
#pragma unroll
            for (int r = 0; r < 4; r++)
                Ob[(w2 * 16 + q * 4 + r) * 65 + ns * 16 + l16] = acc[ns][r];
    }
    __syncthreads();
    if (g == 1) {
        const int t0 = c * 64;
#pragma unroll
        for (int ns = 0; ns < 4; ns++)
#pragma unroll
            for (int r = 0; r < 4; r++) {
                const float sum = acc[ns][r] + Ob[(w2 * 16 + q * 4 + r) * 65 + ns * 16 + l16];
                out[((size_t)b * N_T + t0 + w2 * 16 + q * 4 + r) * NN + ns * 16 + l16] = sum;
            }
    }
}

// ---------------------------------------------------------------------------
extern "C" void kernel_launch(void* const* d_in, const int* in_sizes, int n_in,
                              void* d_out, int out_size, void* d_ws, size_t ws_size,
                              hipStream_t stream) {
    const float* rp = (const float*)d_in[0];   // (8, 2048, 64) fp32
    const float* Qm = (const float*)d_in[1];   // (8, 64, 64)
    const float* Em = (const float*)d_in[2];   // (8, 64, 64)
    float* out = (float*)d_out;                // (8, 2048, 64) fp32

    // ws: ErT bf16 [8,8,64,2048] (16 MiB) + dGb bf16 [8,32,64,64] (2 MiB)
    bf16* ErT = (bf16*)d_ws;
    bf16* dGb = ErT + (size_t)D_B * N_H * NN * N_T;

    hipFuncSetAttribute((const void*)k_fused,
                        hipFuncAttributeMaxDynamicSharedMemorySize, SMEM_BYTES);
    void* args[] = {(void*)&rp, (void*)&Qm, (void*)&Em,
                    (void*)&ErT, (void*)&dGb, (void*)&out};
    hipLaunchCooperativeKernel((void*)k_fused, dim3(N_C, D_B), dim3(512),
                               args, SMEM_BYTES, stream);
}

// Round 3
// 147.338 us; speedup vs baseline: 1.0225x; 1.0225x over previous
//
#include <hip/hip_runtime.h>

// Problem constants
#define D_B 8
#define N_T 2048
#define NN  64
#define N_H 8
#define N_C 32   // u-chunks of 64
#define NP  72   // padded LDS row stride (bf16 elems; 144 B = 16B-aligned rows)

typedef __bf16 bf16;
typedef bf16 bf16x8 __attribute__((ext_vector_type(8)));
typedef bf16 bf16x4 __attribute__((ext_vector_type(4)));
typedef float f32x4 __attribute__((ext_vector_type(4)));

static __device__ __forceinline__ f32x4 mfma16(bf16x8 a, bf16x8 b, f32x4 c) {
    // a_frag[j] = A[lane&15][(lane>>4)*8+j]; b_frag[j] = B[(lane>>4)*8+j][lane&15]
    // d[r] = D[(lane>>4)*4+r][lane&15]
    return __builtin_amdgcn_mfma_f32_16x16x32_bf16(a, b, c, 0, 0, 0);
}

static __device__ __forceinline__ bf16x8 ldcvt8(const float* p) {
    const f32x4 v0 = *(const f32x4*)p;
    const f32x4 v1 = *(const f32x4*)(p + 4);
    bf16x8 r;
#pragma unroll
    for (int k = 0; k < 4; k++) { r[k] = (bf16)v0[k]; r[4 + k] = (bf16)v1[k]; }
    return r;
}

// ---------------------------------------------------------------------------
// K1: block (c, b, qt) handles heads {2qt, 2qt+1}: dG quarter
//   dGqT[b,c,qt][i][i'] = sum_{h in qt} sum_{u in c} Qr[u,i'] Er[u,i]
// (stored i-major so K2/K3 never transpose). Also emits Rbf (qt==0) and
// bf16 Q/E copies (c==0,b==0 blocks). 4 waves, 27.6 KB LDS, 4 blocks/CU.
// ---------------------------------------------------------------------------
__global__ __launch_bounds__(256, 4) void k_dg(
    const float* __restrict__ rp, const float* __restrict__ Qm,
    const float* __restrict__ Em,
    bf16* __restrict__ dGqT, bf16* __restrict__ Rbf,
    bf16* __restrict__ Qbf, bf16* __restrict__ Ebf)
{
    __shared__ bf16 Rl[64 * NP];   // r' chunk [u][j]
    __shared__ bf16 QT[64 * NP];   // Qr tile transposed [i'][u]; later dG^T tile
    __shared__ bf16 ET[64 * NP];   // Er tile transposed [i][u]
    const int c = blockIdx.x, b = blockIdx.y, qt = blockIdx.z;
    const int tid = threadIdx.x;
    const int w = tid >> 6, l = tid & 63, q = l >> 4, l16 = l & 15;

    {
        const int row = tid >> 2, col = (tid & 3) * 16;
        const float* src = rp + ((size_t)b * N_T + c * 64 + row) * NN + col;
        const bf16x8 v0 = ldcvt8(src), v1 = ldcvt8(src + 8);
        *(bf16x8*)&Rl[row * NP + col] = v0;
        *(bf16x8*)&Rl[row * NP + col + 8] = v1;
        if (qt == 0) {
            bf16* d = Rbf + ((size_t)b * N_T + c * 64 + row) * NN + col;
            *(bf16x8*)d = v0;
            *(bf16x8*)(d + 8) = v1;
        }
    }
    if (c == 0 && b == 0) {
        const int e = tid * 16;
#pragma unroll
        for (int hh = 0; hh < 2; hh++) {
            const int h = qt * 2 + hh;
            *(bf16x8*)&Qbf[h * 4096 + e]     = ldcvt8(Qm + h * 4096 + e);
            *(bf16x8*)&Qbf[h * 4096 + e + 8] = ldcvt8(Qm + h * 4096 + e + 8);
            *(bf16x8*)&Ebf[h * 4096 + e]     = ldcvt8(Em + h * 4096 + e);
            *(bf16x8*)&Ebf[h * 4096 + e + 8] = ldcvt8(Em + h * 4096 + e + 8);
        }
    }
    __syncthreads();
    // A-frags: R rows (u-slab w*16)
    const bf16x8 a0 = *(const bf16x8*)&Rl[(w * 16 + l16) * NP + q * 8];
    const bf16x8 a1 = *(const bf16x8*)&Rl[(w * 16 + l16) * NP + 32 + q * 8];

    f32x4 dacc[4];
#pragma unroll
    for (int ns = 0; ns < 4; ns++) { f32x4 z = {0.f, 0.f, 0.f, 0.f}; dacc[ns] = z; }

    for (int hh = 0; hh < 2; hh++) {
        const int h = qt * 2 + hh;
        const float* Qh = Qm + (size_t)h * 4096;
        const float* Eh = Em + (size_t)h * 4096;
#pragma unroll
        for (int ns = 0; ns < 4; ns++) {
            // Qr[u,i'] = sum_j R[u,j] Q[i',j]; B storage [n=i'][k=j] = Q row-major
            bf16x8 b0 = ldcvt8(Qh + (ns * 16 + l16) * 64 + q * 8);
            bf16x8 b1 = ldcvt8(Qh + (ns * 16 + l16) * 64 + 32 + q * 8);
            f32x4 z = {0.f, 0.f, 0.f, 0.f};
            f32x4 s = mfma16(a0, b0, z);
            s = mfma16(a1, b1, s);
            bf16x4 p;
#pragma unroll
            for (int r = 0; r < 4; r++) p[r] = (bf16)s[r];
            *(bf16x4*)&QT[(ns * 16 + l16) * NP + w * 16 + q * 4] = p;  // [i'][u]
            b0 = ldcvt8(Eh + (ns * 16 + l16) * 64 + q * 8);
            b1 = ldcvt8(Eh + (ns * 16 + l16) * 64 + 32 + q * 8);
            f32x4 s2 = mfma16(a0, b0, z);
            s2 = mfma16(a1, b1, s2);
#pragma unroll
            for (int r = 0; r < 4; r++) p[r] = (bf16)s2[r];
            *(bf16x4*)&ET[(ns * 16 + l16) * NP + w * 16 + q * 4] = p;  // [i][u]
        }
        __syncthreads();
        // dG[i'][i] += Qr^T Er : A from QT [i'][u], B from ET [i][u]
        const bf16x8 qa0 = *(const bf16x8*)&QT[(w * 16 + l16) * NP + q * 8];
        const bf16x8 qa1 = *(const bf16x8*)&QT[(w * 16 + l16) * NP + 32 + q * 8];
#pragma unroll
        for (int ns = 0; ns < 4; ns++) {
            const bf16x8 e0 = *(const bf16x8*)&ET[(ns * 16 + l16) * NP + q * 8];
            const bf16x8 e1 = *(const bf16x8*)&ET[(ns * 16 + l16) * NP + 32 + q * 8];
            dacc[ns] = mfma16(qa0, e0, dacc[ns]);
            dacc[ns] = mfma16(qa1, e1, dacc[ns]);
        }
        __syncthreads();   // before next head overwrites QT/ET
    }
    // transpose dacc (row i'=w*16+q*4+r, col i=ns*16+l16) into QT as [i][i']
#pragma unroll
    for (int ns = 0; ns < 4; ns++) {
        bf16x4 p;
#pragma unroll
        for (int r = 0; r < 4; r++) p[r] = (bf16)dacc[ns][r];
        *(bf16x4*)&QT[(ns * 16 + l16) * NP + w * 16 + q * 4] = p;
    }
    __syncthreads();
    {
        bf16* dst = dGqT + (((size_t)(b * N_C + c)) * 4 + qt) * 4096 + tid * 16;
        *(bf16x8*)dst       = *(const bf16x8*)&QT[(tid >> 2) * NP + (tid & 3) * 16];
        *(bf16x8*)(dst + 8) = *(const bf16x8*)&QT[(tid >> 2) * NP + (tid & 3) * 16 + 8];
    }
}

// ---------------------------------------------------------------------------
// K2: Gc[b,c][i][i'] = sum_{c'<c} sum_qt dGqT[b,c',qt][i][i'].
// Pure streaming accumulate, no LDS/barriers. 256 blocks x 256 thr.
// ---------------------------------------------------------------------------
__global__ __launch_bounds__(256, 2) void k_scan(const bf16* __restrict__ dGqT,
                                                 bf16* __restrict__ Gc)
{
    const int c = blockIdx.x, b = blockIdx.y;
    const int tid = threadIdx.x;
    float run[16];
#pragma unroll
    for (int k = 0; k < 16; k++) run[k] = 0.f;
    const bf16* base = dGqT + (size_t)b * N_C * 4 * 4096 + tid * 16;
    for (int cp = 0; cp < c; cp++) {
#pragma unroll
        for (int qt = 0; qt < 4; qt++) {
            const bf16* p = base + ((size_t)(cp * 4 + qt)) * 4096;
            const bf16x8 u0 = *(const bf16x8*)p;
            const bf16x8 u1 = *(const bf16x8*)(p + 8);
#pragma unroll
            for (int k = 0; k < 8; k++) {
                run[k] += (float)u0[k];
                run[8 + k] += (float)u1[k];
            }
        }
    }
    bf16x8 o0, o1;
#pragma unroll
    for (int k = 0; k < 8; k++) { o0[k] = (bf16)run[k]; o1[k] = (bf16)run[8 + k]; }
    bf16* dst = Gc + (size_t)(b * N_C + c) * 4096 + tid * 16;
    *(bf16x8*)dst = o0;
    *(bf16x8*)(dst + 8) = o1;
}

// ---------------------------------------------------------------------------
// K3: block (c, b, half) computes out rows [c*64 + half*32, +32):
//   O = R_t * Gcum  +  sum_h tril(R_t Qr_h^T) Er_h   (diag chunk only)
// Qr/Er diag tiles RECOMPUTED from Rbf/Qbf/Ebf (no 32 MB round-trip).
// 4 waves: ws=w&1 t-sub(16 rows), ih=w>>1 u-half (S) / i-half (S*Er, out).
// ---------------------------------------------------------------------------
__global__ __launch_bounds__(256, 2) void k_out(
    const bf16* __restrict__ Rbf, const bf16* __restrict__ Qbf,
    const bf16* __restrict__ Ebf, const bf16* __restrict__ Gc,
    float* __restrict__ out)
{
    __shared__ bf16 Rl[64 * NP];    // full chunk R [u][j]
    __shared__ bf16 Qrl[64 * NP];   // Qr tile [u][i']  (direct D-layout)
    __shared__ bf16 ET[64 * NP];    // Er tile [i][u]   (transpose-store)
    __shared__ bf16 St[32 * NP];    // masked S [t32][u]
    const int c = blockIdx.x, b = blockIdx.y, half = blockIdx.z;
    const int tid = threadIdx.x;
    const int w = tid >> 6, l = tid & 63, q = l >> 4, l16 = l & 15;
    const int ws = w & 1, ih = w >> 1;
    const int t0 = c * 64 + half * 32;

    {
        const int row = tid >> 2, col = (tid & 3) * 16;
        const bf16* src = Rbf + ((size_t)b * N_T + c * 64 + row) * NN + col;
        *(bf16x8*)&Rl[row * NP + col] = *(const bf16x8*)src;
        *(bf16x8*)&Rl[row * NP + col + 8] = *(const bf16x8*)(src + 8);
    }
    if (half == 0) {
        // upper u-half of St never written when half==0; must read as zeros
        const bf16x8 z8 = {};
        for (int k = tid; k < (32 * NP) / 8; k += 256) *(bf16x8*)&St[k * 8] = z8;
    }
    __syncthreads();
    // tile-build A-frags (u-slab w*16) and S/prefix A-frags (t rows)
    const bf16x8 ua0 = *(const bf16x8*)&Rl[(w * 16 + l16) * NP + q * 8];
    const bf16x8 ua1 = *(const bf16x8*)&Rl[(w * 16 + l16) * NP + 32 + q * 8];
    const bf16x8 ra0 = *(const bf16x8*)&Rl[(half * 32 + ws * 16 + l16) * NP + q * 8];
    const bf16x8 ra1 = *(const bf16x8*)&Rl[(half * 32 + ws * 16 + l16) * NP + 32 + q * 8];

    f32x4 acc[2];
#pragma unroll
    for (int ns = 0; ns < 2; ns++) { f32x4 z = {0.f, 0.f, 0.f, 0.f}; acc[ns] = z; }

    for (int h = 0; h < N_H; h++) {
        const bf16* Qh = Qbf + (size_t)h * 4096;
        const bf16* Eh = Ebf + (size_t)h * 4096;
#pragma unroll
        for (int ns = 0; ns < 4; ns++) {
            const bf16x8 qb0 = *(const bf16x8*)&Qh[(ns * 16 + l16) * 64 + q * 8];
            const bf16x8 qb1 = *(const bf16x8*)&Qh[(ns * 16 + l16) * 64 + 32 + q * 8];
            f32x4 z = {0.f, 0.f, 0.f, 0.f};
            f32x4 s = mfma16(ua0, qb0, z);
            s = mfma16(ua1, qb1, s);
#pragma unroll
            for (int r = 0; r < 4; r++)
                Qrl[(w * 16 + q * 4 + r) * NP + ns * 16 + l16] = (bf16)s[r];  // [u][i']
            const bf16x8 eb0 = *(const bf16x8*)&Eh[(ns * 16 + l16) * 64 + q * 8];
            const bf16x8 eb1 = *(const bf16x8*)&Eh[(ns * 16 + l16) * 64 + 32 + q * 8];
            f32x4 s2 = mfma16(ua0, eb0, z);
            s2 = mfma16(ua1, eb1, s2);
            bf16x4 p;
#pragma unroll
            for (int r = 0; r < 4; r++) p[r] = (bf16)s2[r];
            *(bf16x4*)&ET[(ns * 16 + l16) * NP + w * 16 + q * 4] = p;         // [i][u]
        }
        __syncthreads();
        // S[t][u] = R_t . Qr[u,:] ; wave (ws, ih): t-sub ws, u-half ih
        if (half == 1 || ih == 0) {
#pragma unroll
            for (int ns = 0; ns < 2; ns++) {
                const bf16x8 sb0 = *(const bf16x8*)&Qrl[(ih * 32 + ns * 16 + l16) * NP + q * 8];
                const bf16x8 sb1 = *(const bf16x8*)&Qrl[(ih * 32 + ns * 16 + l16) * NP + 32 + q * 8];
                f32x4 z = {0.f, 0.f, 0.f, 0.f};
                f32x4 sv = mfma16(ra0, sb0, z);
                sv = mfma16(ra1, sb1, sv);
                const int u_rel = ih * 32 + ns * 16 + l16;
#pragma unroll
                for (int r = 0; r < 4; r++) {
                    const int t_rel = half * 32 + ws * 16 + q * 4 + r;
                    St[(ws * 16 + q * 4 + r) * NP + u_rel] =
                        (u_rel <= t_rel) ? (bf16)sv[r] : (bf16)0.f;
                }
            }
        }
        __syncthreads();
        // O += S * Er : A from St [t32][u], B from ET [i][u]
        const bf16x8 sa0 = *(const bf16x8*)&St[(ws * 16 + l16) * NP + q * 8];
#pragma unroll
        for (int ns = 0; ns < 2; ns++) {
            const bf16x8 e0 = *(const bf16x8*)&ET[(ih * 32 + ns * 16 + l16) * NP + q * 8];
            acc[ns] = mfma16(sa0, e0, acc[ns]);
        }
        if (half == 1) {
            const bf16x8 sa1 = *(const bf16x8*)&St[(ws * 16 + l16) * NP + 32 + q * 8];
#pragma unroll
            for (int ns = 0; ns < 2; ns++) {
                const bf16x8 e1 = *(const bf16x8*)&ET[(ih * 32 + ns * 16 + l16) * NP + 32 + q * 8];
                acc[ns] = mfma16(sa1, e1, acc[ns]);
            }
        }
        __syncthreads();   // before next head overwrites Qrl/ET/St
    }
    // prefix: O += R_t * Gcum ; B-frags straight from global Gc [i][i']
    {
        const bf16* Gt = Gc + (size_t)(b * N_C + c) * 4096;
#pragma unroll
        for (int ns = 0; ns < 2; ns++) {
            const bf16x8 g0 = *(const bf16x8*)&Gt[(ih * 32 + ns * 16 + l16) * 64 + q * 8];
            const bf16x8 g1 = *(const bf16x8*)&Gt[(ih * 32 + ns * 16 + l16) * 64 + 32 + q * 8];
            acc[ns] = mfma16(ra0, g0, acc[ns]);
            acc[ns] = mfma16(ra1, g1, acc[ns]);
        }
    }
    // write out (rows t0 + ws*16 + q*4 + r, cols ih*32 + ns*16 + l16)
#pragma unroll
    for (int ns = 0; ns < 2; ns++)
#pragma unroll
        for (int r = 0; r < 4; r++)
            out[((size_t)b * N_T + t0 + ws * 16 + q * 4 + r) * NN + ih * 32 + ns * 16 + l16] =
                acc[ns][r];
}

// ---------------------------------------------------------------------------
extern "C" void kernel_launch(void* const* d_in, const int* in_sizes, int n_in,
                              void* d_out, int out_size, void* d_ws, size_t ws_size,
                              hipStream_t stream) {
    const float* rp = (const float*)d_in[0];   // (8, 2048, 64) fp32
    const float* Qm = (const float*)d_in[1];   // (8, 64, 64)
    const float* Em = (const float*)d_in[2];   // (8, 64, 64)
    float* out = (float*)d_out;                // (8, 2048, 64) fp32

    // ws: dGqT 8.4 MB + Rbf 2 MB + Qbf/Ebf 64 KB each + Gc 2 MB  (~12.5 MB)
    bf16* dGqT = (bf16*)d_ws;
    bf16* Rbf = dGqT + (size_t)D_B * N_C * 4 * 4096;
    bf16* Qbf = Rbf + (size_t)D_B * N_T * NN;
    bf16* Ebf = Qbf + (size_t)N_H * 4096;
    bf16* Gc  = Ebf + (size_t)N_H * 4096;

    k_dg<<<dim3(N_C, D_B, 4), 256, 0, stream>>>(rp, Qm, Em, dGqT, Rbf, Qbf, Ebf);
    k_scan<<<dim3(N_C, D_B), 256, 0, stream>>>(dGqT, Gc);
    k_out<<<dim3(N_C, D_B, 2), 256, 0, stream>>>(Rbf, Qbf, Ebf, Gc, out);
}

// Round 4
// 110.700 us; speedup vs baseline: 1.3609x; 1.3310x over previous
//
#include <hip/hip_runtime.h>

// Problem constants
#define D_B 8
#define N_T 2048
#define NN  64
#define N_H 8
#define N_C 32   // u-chunks of 64
#define NP  72   // padded LDS row stride (bf16): 144 B rows -> 2-way bank alias (free)

typedef __bf16 bf16;
typedef bf16 bf16x8 __attribute__((ext_vector_type(8)));
typedef bf16 bf16x4 __attribute__((ext_vector_type(4)));
typedef float f32x4 __attribute__((ext_vector_type(4)));

static __device__ __forceinline__ f32x4 mfma16(bf16x8 a, bf16x8 b, f32x4 c) {
    // a_frag[j] = A[lane&15][(lane>>4)*8+j]; b_frag[j] = B[(lane>>4)*8+j][lane&15]
    // d[r] = D[(lane>>4)*4+r][lane&15]
    return __builtin_amdgcn_mfma_f32_16x16x32_bf16(a, b, c, 0, 0, 0);
}

static __device__ __forceinline__ bf16x8 ldcvt8(const float* p) {
    const f32x4 v0 = *(const f32x4*)p;
    const f32x4 v1 = *(const f32x4*)(p + 4);
    bf16x8 r;
#pragma unroll
    for (int k = 0; k < 4; k++) { r[k] = (bf16)v0[k]; r[4 + k] = (bf16)v1[k]; }
    return r;
}

// ---------------------------------------------------------------------------
// K1: block (b, c, qt) handles heads {2qt, 2qt+1} of chunk c:
//   Qrd[b,c,h][u][i'] = sum_j R[u,j] Q[h,i',j]   (diag-chunk-blocked)
//   Erd[b,c,h][i][u]  = sum_j R[u,j] E[h,i,j]    (transposed, coalesced 8KB)
//   dGq[b,c,qt][i][i'] = sum_h sum_u Qr[u,i'] Er[u,i]  (bf16, pre-transposed)
//   Rbf (qt==0). Q/E staged fp32->bf16 through LDS (clean ds_read_b128 B-frags).
// Grid (D_B, N_C, 4): linear%8 = b -> all chunks of batch b on one XCD.
// ---------------------------------------------------------------------------
__global__ __launch_bounds__(256, 3) void k_dg(
    const float* __restrict__ rp, const float* __restrict__ Qm,
    const float* __restrict__ Em,
    bf16* __restrict__ dGq, bf16* __restrict__ Rbf,
    bf16* __restrict__ Qrd, bf16* __restrict__ Erd)
{
    __shared__ bf16 Rl[64 * NP];   // R chunk [u][j]
    __shared__ bf16 Ql[64 * NP];   // Q_h [i'][j]
    __shared__ bf16 El[64 * NP];   // E_h [i][j]
    __shared__ bf16 QT[64 * NP];   // Qr tile [i'][u]; later dG [i][i'] staging
    __shared__ bf16 ET[64 * NP];   // Er tile [i][u]
    const int b = blockIdx.x, c = blockIdx.y, qt = blockIdx.z;
    const int tid = threadIdx.x;
    const int w = tid >> 6, l = tid & 63, q = l >> 4, l16 = l & 15;
    const int row = tid >> 2, col = (tid & 3) * 16;

    {
        const float* src = rp + ((size_t)b * N_T + c * 64 + row) * NN + col;
        const bf16x8 v0 = ldcvt8(src), v1 = ldcvt8(src + 8);
        *(bf16x8*)&Rl[row * NP + col] = v0;
        *(bf16x8*)&Rl[row * NP + col + 8] = v1;
        if (qt == 0) {
            bf16* d = Rbf + ((size_t)b * N_T + c * 64 + row) * NN + col;
            *(bf16x8*)d = v0;
            *(bf16x8*)(d + 8) = v1;
        }
    }
    __syncthreads();
    // A-frags: R rows, u-slab w*16
    const bf16x8 a0 = *(const bf16x8*)&Rl[(w * 16 + l16) * NP + q * 8];
    const bf16x8 a1 = *(const bf16x8*)&Rl[(w * 16 + l16) * NP + 32 + q * 8];

    f32x4 dacc[4];
#pragma unroll
    for (int ns = 0; ns < 4; ns++) { f32x4 z = {0.f, 0.f, 0.f, 0.f}; dacc[ns] = z; }

    for (int hh = 0; hh < 2; hh++) {
        const int h = qt * 2 + hh;
        // stage Q_h/E_h fp32 -> bf16 LDS (coalesced row loads)
        {
            const float* qs = Qm + (size_t)h * 4096 + row * 64 + col;
            const float* es = Em + (size_t)h * 4096 + row * 64 + col;
            *(bf16x8*)&Ql[row * NP + col]     = ldcvt8(qs);
            *(bf16x8*)&Ql[row * NP + col + 8] = ldcvt8(qs + 8);
            *(bf16x8*)&El[row * NP + col]     = ldcvt8(es);
            *(bf16x8*)&El[row * NP + col + 8] = ldcvt8(es + 8);
        }
        __syncthreads();
        const size_t tb = (((size_t)(b * N_C + c)) * N_H + h) * 4096;
#pragma unroll
        for (int ns = 0; ns < 4; ns++) {
            // Qr[u,i'] : B storage [n=i'][k=j] = Ql
            bf16x8 b0 = *(const bf16x8*)&Ql[(ns * 16 + l16) * NP + q * 8];
            bf16x8 b1 = *(const bf16x8*)&Ql[(ns * 16 + l16) * NP + 32 + q * 8];
            f32x4 z = {0.f, 0.f, 0.f, 0.f};
            f32x4 s = mfma16(a0, b0, z);
            s = mfma16(a1, b1, s);
            bf16x4 p;
#pragma unroll
            for (int r = 0; r < 4; r++) p[r] = (bf16)s[r];
            // Qrd global direct (row=u, col=i'): 32-B segments
#pragma unroll
            for (int r = 0; r < 4; r++)
                Qrd[tb + (w * 16 + q * 4 + r) * 64 + ns * 16 + l16] = p[r];
            *(bf16x4*)&QT[(ns * 16 + l16) * NP + w * 16 + q * 4] = p;  // [i'][u]
            // Er[u,i]
            b0 = *(const bf16x8*)&El[(ns * 16 + l16) * NP + q * 8];
            b1 = *(const bf16x8*)&El[(ns * 16 + l16) * NP + 32 + q * 8];
            f32x4 s2 = mfma16(a0, b0, z);
            s2 = mfma16(a1, b1, s2);
#pragma unroll
            for (int r = 0; r < 4; r++) p[r] = (bf16)s2[r];
            *(bf16x4*)&ET[(ns * 16 + l16) * NP + w * 16 + q * 4] = p;  // [i][u]
        }
        __syncthreads();
        // dG[i'][i] += Qr^T Er : A from QT [i'][u], B from ET [i][u]
        {
            const bf16x8 qa0 = *(const bf16x8*)&QT[(w * 16 + l16) * NP + q * 8];
            const bf16x8 qa1 = *(const bf16x8*)&QT[(w * 16 + l16) * NP + 32 + q * 8];
#pragma unroll
            for (int ns = 0; ns < 4; ns++) {
                const bf16x8 e0 = *(const bf16x8*)&ET[(ns * 16 + l16) * NP + q * 8];
                const bf16x8 e1 = *(const bf16x8*)&ET[(ns * 16 + l16) * NP + 32 + q * 8];
                dacc[ns] = mfma16(qa0, e0, dacc[ns]);
                dacc[ns] = mfma16(qa1, e1, dacc[ns]);
            }
        }
        // Erd coalesced copy from ET (8 KB contiguous)
        {
            const bf16x8 v0 = *(const bf16x8*)&ET[row * NP + col];
            const bf16x8 v1 = *(const bf16x8*)&ET[row * NP + col + 8];
            bf16* d = Erd + tb + row * 64 + col;
            *(bf16x8*)d = v0;
            *(bf16x8*)(d + 8) = v1;
        }
        __syncthreads();   // QT/ET/Ql/El reads done before next head overwrites
    }
    // transpose dacc (D row=i', col=i) -> QT as [i][i'], then coalesced store
#pragma unroll
    for (int ns = 0; ns < 4; ns++) {
        bf16x4 p;
#pragma unroll
        for (int r = 0; r < 4; r++) p[r] = (bf16)dacc[ns][r];
        *(bf16x4*)&QT[(ns * 16 + l16) * NP + w * 16 + q * 4] = p;
    }
    __syncthreads();
    {
        bf16* dst = dGq + (((size_t)(b * N_C + c)) * 4 + qt) * 4096 + row * 64 + col;
        *(bf16x8*)dst       = *(const bf16x8*)&QT[row * NP + col];
        *(bf16x8*)(dst + 8) = *(const bf16x8*)&QT[row * NP + col + 8];
    }
}

// ---------------------------------------------------------------------------
// K2: block (b, c): inline exclusive scan of dGq -> Gb LDS, then R1's
// barrier-free head loop: S = tril(R_t Qr^T) -> LDS (same-wave RAW) -> S*Er,
// plus prefix term R_t*Gcum; two h-groups reduced via LDS.
// Grid (D_B, N_C): linear%8 = b -> reads hit the XCD-local L2 K1 wrote.
// ---------------------------------------------------------------------------
__global__ __launch_bounds__(512, 2) void k_out(
    const bf16* __restrict__ dGq, const bf16* __restrict__ Rbf,
    const bf16* __restrict__ Qrd, const bf16* __restrict__ Erd,
    float* __restrict__ out)
{
    __shared__ bf16 Gb[64 * NP];            // Gcum [i][i']
    __shared__ char sm2[8 * 16 * NP * 2];   // S slabs (18432 B) / Ob (16640 B)
    bf16* Sl = (bf16*)sm2;
    float* Ob = (float*)sm2;
    const int b = blockIdx.x, c = blockIdx.y;
    const int tid = threadIdx.x;
    const int w = tid >> 6, l = tid & 63, q = l >> 4, l16 = l & 15;
    const int g = w >> 2, s = w & 3;

    // ---- inline exclusive scan: Gcum = sum_{c'<c, qt} dGq[b,c',qt]
    {
        float run[8];
#pragma unroll
        for (int k = 0; k < 8; k++) run[k] = 0.f;
        const bf16* base = dGq + (size_t)b * N_C * 4 * 4096 + tid * 8;
        for (int cp = 0; cp < c; cp++) {
#pragma unroll
            for (int qt = 0; qt < 4; qt++) {
                const bf16x8 v = *(const bf16x8*)(base + ((size_t)(cp * 4 + qt)) * 4096);
#pragma unroll
                for (int k = 0; k < 8; k++) run[k] += (float)v[k];
            }
        }
        bf16x8 o;
#pragma unroll
        for (int k = 0; k < 8; k++) o[k] = (bf16)run[k];
        *(bf16x8*)&Gb[(tid >> 3) * NP + (tid & 7) * 8] = o;   // [i][i']
    }
    __syncthreads();

    // A-frags: R rows t = c*64 + s*16 + l16 (global gather, 128-B row stride)
    const bf16x8 ra0 = *(const bf16x8*)&Rbf[((size_t)b * N_T + c * 64 + s * 16 + l16) * NN + q * 8];
    const bf16x8 ra1 = *(const bf16x8*)&Rbf[((size_t)b * N_T + c * 64 + s * 16 + l16) * NN + 32 + q * 8];

    bf16* Sw = Sl + w * 16 * NP;
    f32x4 acc[4];
#pragma unroll
    for (int ns = 0; ns < 4; ns++) { f32x4 z = {0.f, 0.f, 0.f, 0.f}; acc[ns] = z; }

    for (int hh = 0; hh < 4; hh++) {
        const int h = g * 4 + hh;
        const bf16* Qh = Qrd + (((size_t)(b * N_C + c)) * N_H + h) * 4096;  // [u][i']
        const bf16* Eh = Erd + (((size_t)(b * N_C + c)) * N_H + h) * 4096;  // [i][u]
        // S[t][u] = sum_i' R[t,i'] Qr[u,i'], masked, -> per-wave LDS slab
#pragma unroll
        for (int ns = 0; ns < 4; ns++) {
            const bf16x8 b0 = *(const bf16x8*)&Qh[(ns * 16 + l16) * 64 + q * 8];
            const bf16x8 b1 = *(const bf16x8*)&Qh[(ns * 16 + l16) * 64 + 32 + q * 8];
            f32x4 z = {0.f, 0.f, 0.f, 0.f};
            f32x4 sv = mfma16(ra0, b0, z);
            sv = mfma16(ra1, b1, sv);
            const int u_loc = ns * 16 + l16;
#pragma unroll
            for (int r = 0; r < 4; r++) {
                const int t_loc = s * 16 + q * 4 + r;
                Sw[(q * 4 + r) * NP + u_loc] = (u_loc <= t_loc) ? (bf16)sv[r] : (bf16)0.f;
            }
        }
        // same-wave LDS RAW; S back as A-operand
        const bf16x8 sa0 = *(const bf16x8*)&Sw[l16 * NP + q * 8];
        const bf16x8 sa1 = *(const bf16x8*)&Sw[l16 * NP + 32 + q * 8];
#pragma unroll
        for (int ns = 0; ns < 4; ns++) {
            const bf16x8 e0 = *(const bf16x8*)&Eh[(ns * 16 + l16) * 64 + q * 8];
            const bf16x8 e1 = *(const bf16x8*)&Eh[(ns * 16 + l16) * 64 + 32 + q * 8];
            acc[ns] = mfma16(sa0, e0, acc[ns]);
            acc[ns] = mfma16(sa1, e1, acc[ns]);
        }
    }
    // prefix term (g==1 only): O += R_t * Gcum, B storage [n=i][k=i'] = Gb
    if (g == 1) {
#pragma unroll
        for (int ns = 0; ns < 4; ns++) {
            const bf16x8 g0 = *(const bf16x8*)&Gb[(ns * 16 + l16) * NP + q * 8];
            const bf16x8 g1 = *(const bf16x8*)&Gb[(ns * 16 + l16) * NP + 32 + q * 8];
            acc[ns] = mfma16(ra0, g0, acc[ns]);
            acc[ns] = mfma16(ra1, g1, acc[ns]);
        }
    }
    __syncthreads();   // all S reads done before Ob overwrites the region
    if (g == 0) {
#pragma unroll
        for (int ns = 0; ns < 4; ns++)
#pragma unroll
            for (int r = 0; r < 4; r++)
                Ob[(s * 16 + q * 4 + r) * 65 + ns * 16 + l16] = acc[ns][r];
    }
    __syncthreads();
    if (g == 1) {
        const int t0 = c * 64;
#pragma unroll
        for (int ns = 0; ns < 4; ns++)
#pragma unroll
            for (int r = 0; r < 4; r++) {
                const float sum = acc[ns][r] + Ob[(s * 16 + q * 4 + r) * 65 + ns * 16 + l16];
                out[((size_t)b * N_T + t0 + s * 16 + q * 4 + r) * NN + ns * 16 + l16] = sum;
            }
    }
}

// ---------------------------------------------------------------------------
extern "C" void kernel_launch(void* const* d_in, const int* in_sizes, int n_in,
                              void* d_out, int out_size, void* d_ws, size_t ws_size,
                              hipStream_t stream) {
    const float* rp = (const float*)d_in[0];   // (8, 2048, 64) fp32
    const float* Qm = (const float*)d_in[1];   // (8, 64, 64)
    const float* Em = (const float*)d_in[2];   // (8, 64, 64)
    float* out = (float*)d_out;                // (8, 2048, 64) fp32

    // ws: dGq 8.4 MB + Rbf 2 MB + Qrd 16.8 MB + Erd 16.8 MB  (~44 MB)
    bf16* dGq = (bf16*)d_ws;
    bf16* Rbf = dGq + (size_t)D_B * N_C * 4 * 4096;
    bf16* Qrd = Rbf + (size_t)D_B * N_T * NN;
    bf16* Erd = Qrd + (size_t)D_B * N_C * N_H * 4096;

    k_dg<<<dim3(D_B, N_C, 4), 256, 0, stream>>>(rp, Qm, Em, dGq, Rbf, Qrd, Erd);
    k_out<<<dim3(D_B, N_C), 512, 0, stream>>>(dGq, Rbf, Qrd, Erd, out);
}

// Round 5
// 107.609 us; speedup vs baseline: 1.4000x; 1.0287x over previous
//
#include <hip/hip_runtime.h>

// Problem constants
#define D_B 8
#define N_T 2048
#define NN  64
#define N_H 8
#define N_C 32   // u-chunks of 64
#define NP  72   // padded LDS row stride (bf16): 144 B rows -> 2-way bank alias (free)

typedef __bf16 bf16;
typedef bf16 bf16x8 __attribute__((ext_vector_type(8)));
typedef bf16 bf16x4 __attribute__((ext_vector_type(4)));
typedef float f32x4 __attribute__((ext_vector_type(4)));

static __device__ __forceinline__ f32x4 mfma16(bf16x8 a, bf16x8 b, f32x4 c) {
    // a_frag[j] = A[lane&15][(lane>>4)*8+j]; b_frag[j] = B[(lane>>4)*8+j][lane&15]
    // d[r] = D[(lane>>4)*4+r][lane&15]
    return __builtin_amdgcn_mfma_f32_16x16x32_bf16(a, b, c, 0, 0, 0);
}

static __device__ __forceinline__ bf16x8 ldcvt8(const float* p) {
    const f32x4 v0 = *(const f32x4*)p;
    const f32x4 v1 = *(const f32x4*)(p + 4);
    bf16x8 r;
#pragma unroll
    for (int k = 0; k < 4; k++) { r[k] = (bf16)v0[k]; r[4 + k] = (bf16)v1[k]; }
    return r;
}

// ---------------------------------------------------------------------------
// K1 (unchanged from R4): block (b, c, qt) handles heads {2qt, 2qt+1}:
//   Qrd[b,c,h][u][i'], Erd[b,c,h][i][u], dGq[b,c,qt][i][i'], Rbf.
// Grid (D_B, N_C, 4): linear%8 = b -> per-batch XCD L2 locality.
// ---------------------------------------------------------------------------
__global__ __launch_bounds__(256, 3) void k_dg(
    const float* __restrict__ rp, const float* __restrict__ Qm,
    const float* __restrict__ Em,
    bf16* __restrict__ dGq, bf16* __restrict__ Rbf,
    bf16* __restrict__ Qrd, bf16* __restrict__ Erd)
{
    __shared__ bf16 Rl[64 * NP];   // R chunk [u][j]
    __shared__ bf16 Ql[64 * NP];   // Q_h [i'][j]
    __shared__ bf16 El[64 * NP];   // E_h [i][j]
    __shared__ bf16 QT[64 * NP];   // Qr tile [i'][u]; later dG [i][i'] staging
    __shared__ bf16 ET[64 * NP];   // Er tile [i][u]
    const int b = blockIdx.x, c = blockIdx.y, qt = blockIdx.z;
    const int tid = threadIdx.x;
    const int w = tid >> 6, l = tid & 63, q = l >> 4, l16 = l & 15;
    const int row = tid >> 2, col = (tid & 3) * 16;

    {
        const float* src = rp + ((size_t)b * N_T + c * 64 + row) * NN + col;
        const bf16x8 v0 = ldcvt8(src), v1 = ldcvt8(src + 8);
        *(bf16x8*)&Rl[row * NP + col] = v0;
        *(bf16x8*)&Rl[row * NP + col + 8] = v1;
        if (qt == 0) {
            bf16* d = Rbf + ((size_t)b * N_T + c * 64 + row) * NN + col;
            *(bf16x8*)d = v0;
            *(bf16x8*)(d + 8) = v1;
        }
    }
    __syncthreads();
    const bf16x8 a0 = *(const bf16x8*)&Rl[(w * 16 + l16) * NP + q * 8];
    const bf16x8 a1 = *(const bf16x8*)&Rl[(w * 16 + l16) * NP + 32 + q * 8];

    f32x4 dacc[4];
#pragma unroll
    for (int ns = 0; ns < 4; ns++) { f32x4 z = {0.f, 0.f, 0.f, 0.f}; dacc[ns] = z; }

    for (int hh = 0; hh < 2; hh++) {
        const int h = qt * 2 + hh;
        {
            const float* qs = Qm + (size_t)h * 4096 + row * 64 + col;
            const float* es = Em + (size_t)h * 4096 + row * 64 + col;
            *(bf16x8*)&Ql[row * NP + col]     = ldcvt8(qs);
            *(bf16x8*)&Ql[row * NP + col + 8] = ldcvt8(qs + 8);
            *(bf16x8*)&El[row * NP + col]     = ldcvt8(es);
            *(bf16x8*)&El[row * NP + col + 8] = ldcvt8(es + 8);
        }
        __syncthreads();
        const size_t tb = (((size_t)(b * N_C + c)) * N_H + h) * 4096;
#pragma unroll
        for (int ns = 0; ns < 4; ns++) {
            bf16x8 b0 = *(const bf16x8*)&Ql[(ns * 16 + l16) * NP + q * 8];
            bf16x8 b1 = *(const bf16x8*)&Ql[(ns * 16 + l16) * NP + 32 + q * 8];
            f32x4 z = {0.f, 0.f, 0.f, 0.f};
            f32x4 s = mfma16(a0, b0, z);
            s = mfma16(a1, b1, s);
            bf16x4 p;
#pragma unroll
            for (int r = 0; r < 4; r++) p[r] = (bf16)s[r];
#pragma unroll
            for (int r = 0; r < 4; r++)
                Qrd[tb + (w * 16 + q * 4 + r) * 64 + ns * 16 + l16] = p[r];
            *(bf16x4*)&QT[(ns * 16 + l16) * NP + w * 16 + q * 4] = p;  // [i'][u]
            b0 = *(const bf16x8*)&El[(ns * 16 + l16) * NP + q * 8];
            b1 = *(const bf16x8*)&El[(ns * 16 + l16) * NP + 32 + q * 8];
            f32x4 s2 = mfma16(a0, b0, z);
            s2 = mfma16(a1, b1, s2);
#pragma unroll
            for (int r = 0; r < 4; r++) p[r] = (bf16)s2[r];
            *(bf16x4*)&ET[(ns * 16 + l16) * NP + w * 16 + q * 4] = p;  // [i][u]
        }
        __syncthreads();
        {
            const bf16x8 qa0 = *(const bf16x8*)&QT[(w * 16 + l16) * NP + q * 8];
            const bf16x8 qa1 = *(const bf16x8*)&QT[(w * 16 + l16) * NP + 32 + q * 8];
#pragma unroll
            for (int ns = 0; ns < 4; ns++) {
                const bf16x8 e0 = *(const bf16x8*)&ET[(ns * 16 + l16) * NP + q * 8];
                const bf16x8 e1 = *(const bf16x8*)&ET[(ns * 16 + l16) * NP + 32 + q * 8];
                dacc[ns] = mfma16(qa0, e0, dacc[ns]);
                dacc[ns] = mfma16(qa1, e1, dacc[ns]);
            }
        }
        {
            const bf16x8 v0 = *(const bf16x8*)&ET[row * NP + col];
            const bf16x8 v1 = *(const bf16x8*)&ET[row * NP + col + 8];
            bf16* d = Erd + tb + row * 64 + col;
            *(bf16x8*)d = v0;
            *(bf16x8*)(d + 8) = v1;
        }
        __syncthreads();
    }
#pragma unroll
    for (int ns = 0; ns < 4; ns++) {
        bf16x4 p;
#pragma unroll
        for (int r = 0; r < 4; r++) p[r] = (bf16)dacc[ns][r];
        *(bf16x4*)&QT[(ns * 16 + l16) * NP + w * 16 + q * 4] = p;
    }
    __syncthreads();
    {
        bf16* dst = dGq + (((size_t)(b * N_C + c)) * 4 + qt) * 4096 + row * 64 + col;
        *(bf16x8*)dst       = *(const bf16x8*)&QT[row * NP + col];
        *(bf16x8*)(dst + 8) = *(const bf16x8*)&QT[row * NP + col + 8];
    }
}

// ---------------------------------------------------------------------------
// K2 (new): fold the 4 head-quarters: dG8[b,c] = sum_qt dGq[b,c,qt].
// Grid (D_B, N_C) -> linear%8 = b (XCD-local). 256 thr x 16 elems.
// ---------------------------------------------------------------------------
__global__ __launch_bounds__(256, 4) void k_fold(const bf16* __restrict__ dGq,
                                                 bf16* __restrict__ dG8)
{
    const int b = blockIdx.x, c = blockIdx.y;
    const size_t base = ((size_t)(b * N_C + c)) * 4 * 4096 + threadIdx.x * 16;
    float s[16];
#pragma unroll
    for (int k = 0; k < 16; k++) s[k] = 0.f;
#pragma unroll
    for (int qt = 0; qt < 4; qt++) {
        const bf16x8 v0 = *(const bf16x8*)(dGq + base + (size_t)qt * 4096);
        const bf16x8 v1 = *(const bf16x8*)(dGq + base + (size_t)qt * 4096 + 8);
#pragma unroll
        for (int k = 0; k < 8; k++) { s[k] += (float)v0[k]; s[8 + k] += (float)v1[k]; }
    }
    bf16x8 o0, o1;
#pragma unroll
    for (int k = 0; k < 8; k++) { o0[k] = (bf16)s[k]; o1[k] = (bf16)s[8 + k]; }
    bf16* dst = dG8 + (size_t)(b * N_C + c) * 4096 + threadIdx.x * 16;
    *(bf16x8*)dst = o0;
    *(bf16x8*)(dst + 8) = o1;
}

// ---------------------------------------------------------------------------
// K3: block (b, c, half) computes out rows [c*64 + half*32, +32):
//   inline scan of folded dG8 -> Gb; then barrier-free head loop with
//   per-wave private S slabs. half=0 skips the masked-out upper u-range
//   (half the S MFMAs and B-frag loads). 4 waves: s=w&1 t-sub, g=w>>1 h-group.
// Grid (D_B, N_C, 2): linear%8 = b; 512 blocks -> 2 blocks/CU.
// ---------------------------------------------------------------------------
__global__ __launch_bounds__(256, 4) void k_out(
    const bf16* __restrict__ dG8, const bf16* __restrict__ Rbf,
    const bf16* __restrict__ Qrd, const bf16* __restrict__ Erd,
    float* __restrict__ out)
{
    __shared__ bf16 Gb[64 * NP];      // Gcum [i][i']
    __shared__ bf16 Sl[4 * 16 * NP];  // per-wave S slabs
    __shared__ float Ob[32 * 65];     // h-group reduction
    const int b = blockIdx.x, c = blockIdx.y, half = blockIdx.z;
    const int tid = threadIdx.x;
    const int w = tid >> 6, l = tid & 63, q = l >> 4, l16 = l & 15;
    const int s = w & 1, g = w >> 1;

    // ---- inline exclusive scan over folded tiles (<=31 x 16B per thread)
    {
        float run[16];
#pragma unroll
        for (int k = 0; k < 16; k++) run[k] = 0.f;
        const bf16* base = dG8 + (size_t)b * N_C * 4096 + tid * 16;
        for (int cp = 0; cp < c; cp++) {
            const bf16x8 v0 = *(const bf16x8*)(base + (size_t)cp * 4096);
            const bf16x8 v1 = *(const bf16x8*)(base + (size_t)cp * 4096 + 8);
#pragma unroll
            for (int k = 0; k < 8; k++) { run[k] += (float)v0[k]; run[8 + k] += (float)v1[k]; }
        }
        // elem idx = tid*16+k -> i = tid>>2, i' = (tid&3)*16 + k
        bf16x8 o0, o1;
#pragma unroll
        for (int k = 0; k < 8; k++) { o0[k] = (bf16)run[k]; o1[k] = (bf16)run[8 + k]; }
        *(bf16x8*)&Gb[(tid >> 2) * NP + (tid & 3) * 16] = o0;
        *(bf16x8*)&Gb[(tid >> 2) * NP + (tid & 3) * 16 + 8] = o1;
    }
    __syncthreads();

    // A-frags: R rows t = c*64 + half*32 + s*16 + l16
    const int trow = c * 64 + half * 32 + s * 16 + l16;
    const bf16x8 ra0 = *(const bf16x8*)&Rbf[((size_t)b * N_T + trow) * NN + q * 8];
    const bf16x8 ra1 = *(const bf16x8*)&Rbf[((size_t)b * N_T + trow) * NN + 32 + q * 8];

    bf16* Sw = Sl + w * 16 * NP;
    const int NU = half ? 4 : 2;   // u-tiles needed under the causal mask
    f32x4 acc[4];
#pragma unroll
    for (int ns = 0; ns < 4; ns++) { f32x4 z = {0.f, 0.f, 0.f, 0.f}; acc[ns] = z; }

    for (int hh = 0; hh < 4; hh++) {
        const int h = g * 4 + hh;
        const bf16* Qh = Qrd + (((size_t)(b * N_C + c)) * N_H + h) * 4096;  // [u][i']
        const bf16* Eh = Erd + (((size_t)(b * N_C + c)) * N_H + h) * 4096;  // [i][u]
        // S[t][u] = sum_i' R[t,i'] Qr[u,i'], masked -> per-wave slab
        for (int nu = 0; nu < NU; nu++) {
            const bf16x8 b0 = *(const bf16x8*)&Qh[(nu * 16 + l16) * 64 + q * 8];
            const bf16x8 b1 = *(const bf16x8*)&Qh[(nu * 16 + l16) * 64 + 32 + q * 8];
            f32x4 z = {0.f, 0.f, 0.f, 0.f};
            f32x4 sv = mfma16(ra0, b0, z);
            sv = mfma16(ra1, b1, sv);
            const int u_loc = nu * 16 + l16;
#pragma unroll
            for (int r = 0; r < 4; r++) {
                const int t_loc = half * 32 + s * 16 + q * 4 + r;
                Sw[(q * 4 + r) * NP + u_loc] = (u_loc <= t_loc) ? (bf16)sv[r] : (bf16)0.f;
            }
        }
        // same-wave LDS RAW (in-order DS per wave); S back as A-operand
        const bf16x8 sa0 = *(const bf16x8*)&Sw[l16 * NP + q * 8];
#pragma unroll
        for (int ns = 0; ns < 4; ns++) {
            const bf16x8 e0 = *(const bf16x8*)&Eh[(ns * 16 + l16) * 64 + q * 8];
            acc[ns] = mfma16(sa0, e0, acc[ns]);
        }
        if (half) {
            const bf16x8 sa1 = *(const bf16x8*)&Sw[l16 * NP + 32 + q * 8];
#pragma unroll
            for (int ns = 0; ns < 4; ns++) {
                const bf16x8 e1 = *(const bf16x8*)&Eh[(ns * 16 + l16) * 64 + 32 + q * 8];
                acc[ns] = mfma16(sa1, e1, acc[ns]);
            }
        }
    }
    // prefix term (g==1): O += R_t * Gcum, B storage [n=i][k=i'] = Gb
    if (g == 1) {
#pragma unroll
        for (int ns = 0; ns < 4; ns++) {
            const bf16x8 g0 = *(const bf16x8*)&Gb[(ns * 16 + l16) * NP + q * 8];
            const bf16x8 g1 = *(const bf16x8*)&Gb[(ns * 16 + l16) * NP + 32 + q * 8];
            acc[ns] = mfma16(ra0, g0, acc[ns]);
            acc[ns] = mfma16(ra1, g1, acc[ns]);
        }
    }
    if (g == 0) {
#pragma unroll
        for (int ns = 0; ns < 4; ns++)
#pragma unroll
            for (int r = 0; r < 4; r++)
                Ob[(s * 16 + q * 4 + r) * 65 + ns * 16 + l16] = acc[ns][r];
    }
    __syncthreads();
    if (g == 1) {
        const int t0 = c * 64 + half * 32;
#pragma unroll
        for (int ns = 0; ns < 4; ns++)
#pragma unroll
            for (int r = 0; r < 4; r++) {
                const float sum = acc[ns][r] + Ob[(s * 16 + q * 4 + r) * 65 + ns * 16 + l16];
                out[((size_t)b * N_T + t0 + s * 16 + q * 4 + r) * NN + ns * 16 + l16] = sum;
            }
    }
}

// ---------------------------------------------------------------------------
extern "C" void kernel_launch(void* const* d_in, const int* in_sizes, int n_in,
                              void* d_out, int out_size, void* d_ws, size_t ws_size,
                              hipStream_t stream) {
    const float* rp = (const float*)d_in[0];   // (8, 2048, 64) fp32
    const float* Qm = (const float*)d_in[1];   // (8, 64, 64)
    const float* Em = (const float*)d_in[2];   // (8, 64, 64)
    float* out = (float*)d_out;                // (8, 2048, 64) fp32

    // ws: dGq 8.4 MB + Rbf 2 MB + Qrd 16.8 MB + Erd 16.8 MB + dG8 2.1 MB
    bf16* dGq = (bf16*)d_ws;
    bf16* Rbf = dGq + (size_t)D_B * N_C * 4 * 4096;
    bf16* Qrd = Rbf + (size_t)D_B * N_T * NN;
    bf16* Erd = Qrd + (size_t)D_B * N_C * N_H * 4096;
    bf16* dG8 = Erd + (size_t)D_B * N_C * N_H * 4096;

    k_dg<<<dim3(D_B, N_C, 4), 256, 0, stream>>>(rp, Qm, Em, dGq, Rbf, Qrd, Erd);
    k_fold<<<dim3(D_B, N_C), 256, 0, stream>>>(dGq, dG8);
    k_out<<<dim3(D_B, N_C, 2), 256, 0, stream>>>(dG8, Rbf, Qrd, Erd, out);
}